// Round 15
// baseline (1100.293 us; speedup 1.0000x reference)
//
#include <hip/hip_runtime.h>
#include <math.h>

#define NINT 871           // int(sqrt(3)*2*1.3/STEP) - 1
#define NB 256             // rays
#define NPTS (NB*NINT)     // 222976
#define NUM_EMB 512
#define EMB_DIM 64
#define RESO 64
#define STEP_F 0.005158730158730159f
#define RADIUS_F 1.3f
#define PCC_SC 24.615384615384617f   // RESO/(2*RADIUS)

// ws layout in floats (identical to the round-8/12/14 passing layout)
#define WS_RD    0         // 256*3
#define WS_TN    768       // 256
#define WS_SHM   1024      // 256*9
#define WS_E2    3328      // 512
#define WS_CNT   3840      // 512 (counts, zeroed each call)
#define WS_ELOSS 4352      // 1   (zeroed each call)
#define WS_RGBS  4608      // NPTS float4, ray-major: [ray][s]

__device__ __forceinline__ float wave_reduce_sum(float v) {
    #pragma unroll
    for (int off = 32; off > 0; off >>= 1) v += __shfl_down(v, off, 64);
    return v;
}

// ---------- Kernel A: per-ray setup + emb row norms ----------
__global__ void setup_kernel(const float* __restrict__ rays_o,
                             const float* __restrict__ rays_d,
                             const float* __restrict__ emb,
                             float* __restrict__ ws) {
    int gid = blockIdx.x * blockDim.x + threadIdx.x;
    if (gid < NB) {
        int r = gid;
        float dx = rays_d[r*3+0], dy = rays_d[r*3+1], dz = rays_d[r*3+2];
        float n = sqrtf(dx*dx + dy*dy + dz*dz);
        float rx = dx/n, ry = dy/n, rz = dz/n;
        ws[WS_RD + r*3+0] = rx; ws[WS_RD + r*3+1] = ry; ws[WS_RD + r*3+2] = rz;
        float ox = rays_o[r*3+0], oy = rays_o[r*3+1], oz = rays_o[r*3+2];
        float ivx = 1.0f/rx, ivy = 1.0f/ry, ivz = 1.0f/rz;
        float mnx = fminf((-RADIUS_F - ox)*ivx, (RADIUS_F - ox)*ivx);
        float mny = fminf((-RADIUS_F - oy)*ivy, (RADIUS_F - oy)*ivy);
        float mnz = fminf((-RADIUS_F - oz)*ivz, (RADIUS_F - oz)*ivz);
        float tn = fmaxf(fmaxf(fmaxf(mnx, mny), mnz), 0.0f);
        ws[WS_TN + r] = tn;
        const float C0=0.28209479177387814f, C1=0.4886025119029199f;
        const float C20=1.0925484305920792f, C22=0.31539156525252005f, C24=0.5462742152960396f;
        float x = rx, y = ry, z = rz;
        float sh[9];
        sh[0] = C0;
        sh[1] = -C1*y;
        sh[2] =  C1*z;
        sh[3] = -C1*x;
        sh[4] =  C20*x*y;
        sh[5] = -C20*y*z;
        sh[6] =  C22*(2.0f*z*z - x*x - y*y);
        sh[7] = -C20*x*z;
        sh[8] =  C24*(x*x - y*y);
        #pragma unroll
        for (int j = 0; j < 9; ++j) ws[WS_SHM + r*9 + j] = sh[j];
    }
    int e = gid - NB;
    if (e >= 0 && e < NUM_EMB) {
        float s = 0.0f;
        #pragma unroll 8
        for (int k = 0; k < EMB_DIM; ++k) { float v = emb[e*EMB_DIM + k]; s += v*v; }
        ws[WS_E2 + e] = s;
    }
}

// ---------- Kernel B: cooperative 4-wave block over 64 samples ----------
// lane = sample, wave = work slice. Interp channels and VQ code-ranges are
// split across waves; VQ reads emb from LDS (per-lane ds_read -> wave-split
// can't break scalarization, unlike round 9's global float4s). Cross-wave
// argmin combine is lexicographic (score,index) == exact first-occurrence.
// MLP is column-parallel (round-9-proven). Counts use the round-14 LDS
// histogram, wave-0 gated.
__global__ __launch_bounds__(256, 2) void point_kernel(
    const float* __restrict__ rays_o,
    const float* __restrict__ data,
    const float* __restrict__ emb,
    const float* __restrict__ W1, const float* __restrict__ b1,
    const float* __restrict__ W2, const float* __restrict__ b2,
    const float* __restrict__ W3, const float* __restrict__ b3,
    float* __restrict__ ws)
{
    __shared__ float smem[64*68];   // cls rows -> emb tile -> hist -> h1s/h2s/shds
    __shared__ float lds_e2[64];
    __shared__ float sBest[4][64];
    __shared__ int   sBc[4][64];

    const int tidx = threadIdx.x;   // 0..255
    const int lane = tidx & 63;
    const int wave = tidx >> 6;
    const int ray  = blockIdx.y;
    const int s    = blockIdx.x * 64 + lane;
    const bool live = (s < NINT);
    const int  ss = live ? s : (NINT - 1);

    // wave-uniform ray data
    const float rx = ws[WS_RD + ray*3+0];
    const float ry = ws[WS_RD + ray*3+1];
    const float rz = ws[WS_RD + ray*3+2];
    const float tn = ws[WS_TN + ray];
    const float ox = rays_o[ray*3+0], oy = rays_o[ray*3+1], oz = rays_o[ray*3+2];

    const float t  = tn + STEP_F * (float)ss;
    const float px = ox + t*rx, py = oy + t*ry, pz = oz + t*rz;
    const bool mask = live && (fabsf(px) < RADIUS_F) && (fabsf(py) < RADIUS_F) && (fabsf(pz) < RADIUS_F);

    // ---- dead-block early exit (identical mask in all 4 waves -> uniform) ----
    unsigned long long alive = __ballot(mask);
    if (alive == 0ull) {
        if (wave == 0 && live) {
            float4 z4; z4.x = 0.0f; z4.y = 0.0f; z4.z = 0.0f; z4.w = 0.0f;
            ((float4*)(ws + WS_RGBS))[ray*NINT + s] = z4;
        }
        return;
    }

    // trilinear coords
    float ix = fminf(fmaxf((px/RADIUS_F + 1.0f)*0.5f*63.0f, 0.0f), 63.0f);
    float iy = fminf(fmaxf((py/RADIUS_F + 1.0f)*0.5f*63.0f, 0.0f), 63.0f);
    float iz = fminf(fmaxf((pz/RADIUS_F + 1.0f)*0.5f*63.0f, 0.0f), 63.0f);
    int x0 = (int)floorf(ix); float wx = ix - (float)x0; int x1 = x0+1 > 63 ? 63 : x0+1;
    int y0 = (int)floorf(iy); float wy = iy - (float)y0; int y1 = y0+1 > 63 ? 63 : y0+1;
    int z0 = (int)floorf(iz); float wz = iz - (float)z0; int z1 = z0+1 > 63 ? 63 : z0+1;
    const int b000 = z0*4096 + y0*64 + x0;
    const int dxo = x1 - x0;
    const int dyo = (y1 - y0)*64;
    const int dzo = (z1 - z0)*4096;
    const float omwx = 1.0f-wx, omwy = 1.0f-wy, omwz = 1.0f-wz;

    // ---- interp: wave w does channels [16w,16w+16), rolled, retire to LDS ----
    float* myrow = smem + lane*68;
    {
        const int c0ch = wave*16;
        #pragma unroll 4
        for (int c = c0ch; c < c0ch+16; ++c) {
            const float* dc = data + c*262144 + b000;
            float v000 = dc[0],       v001 = dc[dxo];
            float v010 = dc[dyo],     v011 = dc[dyo+dxo];
            float v100 = dc[dzo],     v101 = dc[dzo+dxo];
            float v110 = dc[dzo+dyo], v111 = dc[dzo+dyo+dxo];
            float c00 = v000*omwx + v001*wx;
            float c01 = v010*omwx + v011*wx;
            float c10 = v100*omwx + v101*wx;
            float c11 = v110*omwx + v111*wx;
            myrow[c] = (c00*omwy + c01*wy)*omwz + (c10*omwy + c11*wy)*wz;
        }
    }
    __syncthreads();

    // ---- every thread rehydrates full coarse[64] for its lane ----
    float coarse[EMB_DIM];
    #pragma unroll
    for (int k4 = 0; k4 < 16; ++k4) {
        float4 v = *(const float4*)(myrow + k4*4);
        coarse[k4*4+0] = v.x; coarse[k4*4+1] = v.y;
        coarse[k4*4+2] = v.z; coarse[k4*4+3] = v.w;
    }
    __syncthreads();   // cls dead; safe to overlay emb tiles

    // ---- VQ: 8 tiles of 64 codes; wave w scans codes [16w,16w+16) per tile ----
    float best = 3.4e38f; int bc = 0;
    for (int tile = 0; tile < 8; ++tile) {
        const int cbase = tile*64;
        {
            const float4* src = (const float4*)(emb + cbase*EMB_DIM);
            float4* dst = (float4*)smem;
            #pragma unroll
            for (int i = 0; i < 4; ++i) dst[tidx + i*256] = src[tidx + i*256];
            if (tidx < 64) lds_e2[tidx] = ws[WS_E2 + cbase + tidx];
        }
        __syncthreads();

        for (int cq = 0; cq < 4; ++cq) {
            const int coff = wave*16 + cq*4;        // tile-local code offset
            const float* e0 = smem + coff*64;
            float d0 = 0.0f, d1 = 0.0f, d2 = 0.0f, d3 = 0.0f;
            #pragma unroll
            for (int k4 = 0; k4 < 16; ++k4) {
                float4 e0v = *(const float4*)(e0 + k4*4);
                float4 e1v = *(const float4*)(e0 + 64 + k4*4);
                float4 e2v = *(const float4*)(e0 + 128 + k4*4);
                float4 e3v = *(const float4*)(e0 + 192 + k4*4);
                float c0v = coarse[4*k4+0], c1v = coarse[4*k4+1];
                float c2v = coarse[4*k4+2], c3v = coarse[4*k4+3];
                d0 = fmaf(c0v, e0v.x, d0); d0 = fmaf(c1v, e0v.y, d0);
                d0 = fmaf(c2v, e0v.z, d0); d0 = fmaf(c3v, e0v.w, d0);
                d1 = fmaf(c0v, e1v.x, d1); d1 = fmaf(c1v, e1v.y, d1);
                d1 = fmaf(c2v, e1v.z, d1); d1 = fmaf(c3v, e1v.w, d1);
                d2 = fmaf(c0v, e2v.x, d2); d2 = fmaf(c1v, e2v.y, d2);
                d2 = fmaf(c2v, e2v.z, d2); d2 = fmaf(c3v, e2v.w, d2);
                d3 = fmaf(c0v, e3v.x, d3); d3 = fmaf(c1v, e3v.y, d3);
                d3 = fmaf(c2v, e3v.z, d3); d3 = fmaf(c3v, e3v.w, d3);
            }
            float s0 = lds_e2[coff+0] - 2.0f*d0;
            float s1 = lds_e2[coff+1] - 2.0f*d1;
            float s2 = lds_e2[coff+2] - 2.0f*d2;
            float s3 = lds_e2[coff+3] - 2.0f*d3;
            int cb = cbase + coff;
            if (s0 < best) { best = s0; bc = cb + 0; }
            if (s1 < best) { best = s1; bc = cb + 1; }
            if (s2 < best) { best = s2; bc = cb + 2; }
            if (s3 < best) { best = s3; bc = cb + 3; }
        }
        __syncthreads();
    }

    // ---- cross-wave argmin combine: lexicographic (score, index) ----
    sBest[wave][lane] = best;
    sBc[wave][lane]   = bc;
    __syncthreads();
    {
        float fb = sBest[0][lane]; int fc = sBc[0][lane];
        #pragma unroll
        for (int w = 1; w < 4; ++w) {
            float b = sBest[w][lane]; int c = sBc[w][lane];
            if (b < fb || (b == fb && c < fc)) { fb = b; fc = c; }
        }
        bc = fc;
    }
    __syncthreads();

    // ---- privatized counts histogram (emb tile region dead), wave-0 gated ----
    {
        float* hist = smem;   // 512 bins
        #pragma unroll
        for (int i = 0; i < 2; ++i) hist[tidx + i*256] = 0.0f;
        __syncthreads();
        if (wave == 0 && mask) atomicAdd(&hist[bc], 1.0f);
        __syncthreads();
        #pragma unroll
        for (int i = 0; i < 2; ++i) {
            float h = hist[tidx + i*256];
            if (h != 0.0f) atomicAdd(&ws[WS_CNT + tidx + i*256], h);
        }
    }
    __syncthreads();   // hist region dead before h1s overlay

    // ---- MLP phase A: wave w computes h1 cols [8w,8w+8) ----
    const int j0 = wave*8;
    float h1_[8];
    #pragma unroll
    for (int u = 0; u < 8; ++u) h1_[u] = b1[j0+u];

    float diff2 = 0.0f;
    {
        const float4* eq4 = (const float4*)(emb + bc*EMB_DIM);
        #pragma unroll
        for (int k4 = 0; k4 < 16; ++k4) {
            float4 q4 = eq4[k4];
            float q[4] = {q4.x, q4.y, q4.z, q4.w};
            #pragma unroll
            for (int u = 0; u < 4; ++u) {
                int k = k4*4 + u;
                float d  = q[u] - coarse[k];
                diff2 += d*d;
                float xv = coarse[k] + d;   // quant_st
                #pragma unroll
                for (int j = 0; j < 8; ++j) h1_[j] = fmaf(xv, W1[k*32 + j0 + j], h1_[j]);
            }
        }
    }
    if (wave == 0) {
        float el = mask ? diff2 : 0.0f;
        el = wave_reduce_sum(el);
        if (lane == 0 && el != 0.0f) atomicAdd(&ws[WS_ELOSS], el);
    }

    // ---- phase B: positional encodings into the wave's h1 columns ----
    {
        float fx = px*PCC_SC + 32.0f; fx = (fx - floorf(fx))*2.0f - 1.0f;
        float fy = py*PCC_SC + 32.0f; fy = (fy - floorf(fy))*2.0f - 1.0f;
        float fz = pz*PCC_SC + 32.0f; fz = (fz - floorf(fz))*2.0f - 1.0f;
        float fv[3] = {fx, fy, fz};
        float dv[3] = {rx, ry, rz};
        #pragma unroll
        for (int a = 0; a < 3; ++a) {
            #pragma unroll
            for (int f = 0; f < 4; ++f) {
                float angf = fv[a] * (float)(1 << f);
                float angd = dv[a] * (float)(1 << f);
                float sf = sinf(angf), cf = cosf(angf);
                float sd = sinf(angd), cd = cosf(angd);
                int rowS = 64 + a*8 + f;
                int rowC = rowS + 4;
                int rowSD = 88 + a*8 + f;
                int rowCD = rowSD + 4;
                #pragma unroll
                for (int j = 0; j < 8; ++j) {
                    h1_[j] = fmaf(sf, W1[rowS*32 + j0 + j], h1_[j]);
                    h1_[j] = fmaf(cf, W1[rowC*32 + j0 + j], h1_[j]);
                    h1_[j] = fmaf(sd, W1[rowSD*32 + j0 + j], h1_[j]);
                    h1_[j] = fmaf(cd, W1[rowCD*32 + j0 + j], h1_[j]);
                }
            }
        }
    }

    // relu + exchange h1 via LDS (stride-33 rows)
    float* h1s = smem;              // [64][33] = 2112 floats
    float* h2s = smem + 64*33;      // [64][33]
    #pragma unroll
    for (int u = 0; u < 8; ++u) h1s[lane*33 + j0 + u] = fmaxf(h1_[u], 0.0f);
    __syncthreads();

    // ---- layer 2: wave w computes h2 cols [8w,8w+8) ----
    float h2_[8];
    #pragma unroll
    for (int u = 0; u < 8; ++u) h2_[u] = b2[j0+u];
    {
        const float* myh1 = h1s + lane*33;
        #pragma unroll
        for (int k = 0; k < 32; ++k) {
            float hv = myh1[k];
            #pragma unroll
            for (int u = 0; u < 8; ++u) h2_[u] = fmaf(hv, W2[k*32 + j0 + u], h2_[u]);
        }
    }
    #pragma unroll
    for (int u = 0; u < 8; ++u) h2s[lane*33 + j0 + u] = fmaxf(h2_[u], 0.0f);
    __syncthreads();

    // ---- layer 3: wave w computes shd cols [7w,7w+7) ----
    float* shds = smem;             // reuse h1s region (dead after layer-2 reads)
    {
        const int j3 = wave*7;
        float shd_[7];
        #pragma unroll
        for (int u = 0; u < 7; ++u) shd_[u] = b3[j3+u];
        const float* myh2 = h2s + lane*33;
        #pragma unroll
        for (int k = 0; k < 32; ++k) {
            float hv = myh2[k];
            #pragma unroll
            for (int u = 0; u < 7; ++u) shd_[u] = fmaf(hv, W3[k*28 + j3 + u], shd_[u]);
        }
        #pragma unroll
        for (int u = 0; u < 7; ++u) shds[lane*33 + j3 + u] = shd_[u];
    }
    __syncthreads();

    // ---- final: wave 0 composes rgb/sigma and stores ----
    if (wave == 0 && live) {
        const float* myshd = shds + lane*33;
        const float mf = mask ? 1.0f : 0.0f;
        float sigma = fmaxf(myshd[27], 0.0f) * mf;

        float shm_[9];
        #pragma unroll
        for (int j = 0; j < 9; ++j) shm_[j] = ws[WS_SHM + ray*9 + j];

        float rgb[3];
        #pragma unroll
        for (int c = 0; c < 3; ++c) {
            float acc = 0.0f;
            #pragma unroll
            for (int j = 0; j < 9; ++j) acc = fmaf(shm_[j], myshd[c*9 + j], acc);
            rgb[c] = fminf(fmaxf(acc*mf + 0.5f, 0.0f), 1.0f);
        }
        float4 o4; o4.x = rgb[0]; o4.y = rgb[1]; o4.z = rgb[2]; o4.w = sigma;
        ((float4*)(ws + WS_RGBS))[ray*NINT + s] = o4;   // ray-major
    }
}

// ---------- Kernel C: per-ray compositing, one wave per ray ----------
__global__ void composite_kernel(const float* __restrict__ ws, float* __restrict__ out) {
    const int lane = threadIdx.x & 63;
    const int wid  = threadIdx.x >> 6;
    const int r = blockIdx.x * (blockDim.x >> 6) + wid;
    if (r >= NB) return;

    const float tn = ws[WS_TN + r];
    const float4* rs = ((const float4*)(ws + WS_RGBS)) + r*NINT;

    const int s0 = lane * 14;
    float T = 1.0f, c0 = 0.0f, c1 = 0.0f, c2 = 0.0f, dep = 0.0f, wsum = 0.0f;
    #pragma unroll 2
    for (int i = 0; i < 14; ++i) {
        int s = s0 + i;
        if (s < NINT) {
            float4 v = rs[s];
            float alpha = 1.0f - expf(-v.w * STEP_F);
            float w = alpha * T;
            c0 += w * v.x; c1 += w * v.y; c2 += w * v.z;
            dep  += w * (tn + STEP_F * (float)s);
            wsum += w;
            T *= (1.0f - alpha + 1e-10f);
        }
    }

    float inc = T;
    #pragma unroll
    for (int off = 1; off < 64; off <<= 1) {
        float o = __shfl_up(inc, off, 64);
        if (lane >= off) inc *= o;
    }
    float excl = __shfl_up(inc, 1, 64);
    if (lane == 0) excl = 1.0f;

    c0 *= excl; c1 *= excl; c2 *= excl; dep *= excl; wsum *= excl;
    c0 = wave_reduce_sum(c0);
    c1 = wave_reduce_sum(c1);
    c2 = wave_reduce_sum(c2);
    dep = wave_reduce_sum(dep);
    wsum = wave_reduce_sum(wsum);

    if (lane == 0) {
        float bg = 1.0f - wsum;
        out[r*3+0] = c0 + bg;
        out[r*3+1] = c1 + bg;
        out[r*3+2] = c2 + bg;
        out[768 + r] = dep;
    }
}

// ---------- Kernel D: loss + perplexity ----------
__global__ void finalize_kernel(const float* __restrict__ ws, float* __restrict__ out) {
    __shared__ float red[512];
    int t = threadIdx.x;
    float c = ws[WS_CNT + t];
    red[t] = c;
    __syncthreads();
    #pragma unroll
    for (int off = 256; off > 0; off >>= 1) {
        if (t < off) red[t] += red[t + off];
        __syncthreads();
    }
    float cnt = fmaxf(red[0], 1.0f);
    __syncthreads();
    float avg = c / cnt;
    red[t] = avg * logf(avg + 1e-10f);
    __syncthreads();
    #pragma unroll
    for (int off = 256; off > 0; off >>= 1) {
        if (t < off) red[t] += red[t + off];
        __syncthreads();
    }
    if (t == 0) {
        out[1024] = 0.25f * ws[WS_ELOSS] / (cnt * 64.0f);
        out[1025] = expf(-red[0]);
    }
}

extern "C" void kernel_launch(void* const* d_in, const int* in_sizes, int n_in,
                              void* d_out, int out_size, void* d_ws, size_t ws_size,
                              hipStream_t stream) {
    const float* rays_o = (const float*)d_in[0];
    const float* rays_d = (const float*)d_in[1];
    // d_in[2] = grid_id (int, unused)
    const float* data   = (const float*)d_in[3];
    const float* emb    = (const float*)d_in[4];
    const float* W1 = (const float*)d_in[5];
    const float* b1 = (const float*)d_in[6];
    const float* W2 = (const float*)d_in[7];
    const float* b2 = (const float*)d_in[8];
    const float* W3 = (const float*)d_in[9];
    const float* b3 = (const float*)d_in[10];
    float* ws  = (float*)d_ws;
    float* out = (float*)d_out;

    // zero the atomic accumulators (counts + eloss) every call
    hipMemsetAsync(ws + WS_CNT, 0, (NUM_EMB + 1) * sizeof(float), stream);

    setup_kernel<<<3, 256, 0, stream>>>(rays_o, rays_d, emb, ws);

    dim3 gB((NINT + 63) / 64, NB);   // 14 x 256 blocks, 256 threads (4 waves / 64 samples)
    point_kernel<<<gB, 256, 0, stream>>>(rays_o, data, emb, W1, b1, W2, b2, W3, b3, ws);

    composite_kernel<<<64, 256, 0, stream>>>(ws, out);
    finalize_kernel<<<1, 512, 0, stream>>>(ws, out);
}

// Round 16
// 506.055 us; speedup vs baseline: 2.1743x; 2.1743x over previous
//
#include <hip/hip_runtime.h>
#include <math.h>

#define NINT 871           // int(sqrt(3)*2*1.3/STEP) - 1
#define NB 256             // rays
#define NPTS (NB*NINT)     // 222976
#define NUM_EMB 512
#define EMB_DIM 64
#define RESO 64
#define STEP_F 0.005158730158730159f
#define RADIUS_F 1.3f
#define PCC_SC 24.615384615384617f   // RESO/(2*RADIUS)

// ws layout in floats (identical to the round-8/12/14 passing layout)
#define WS_RD    0         // 256*3
#define WS_TN    768       // 256
#define WS_SHM   1024      // 256*9
#define WS_E2    3328      // 512
#define WS_CNT   3840      // 512 (counts, zeroed each call)
#define WS_ELOSS 4352      // 1   (zeroed each call)
#define WS_RGBS  4608      // NPTS float4, ray-major: [ray][s]

__device__ __forceinline__ float wave_reduce_sum(float v) {
    #pragma unroll
    for (int off = 32; off > 0; off >>= 1) v += __shfl_down(v, off, 64);
    return v;
}

// ---------- Kernel A: per-ray setup + emb row norms ----------
__global__ void setup_kernel(const float* __restrict__ rays_o,
                             const float* __restrict__ rays_d,
                             const float* __restrict__ emb,
                             float* __restrict__ ws) {
    int gid = blockIdx.x * blockDim.x + threadIdx.x;
    if (gid < NB) {
        int r = gid;
        float dx = rays_d[r*3+0], dy = rays_d[r*3+1], dz = rays_d[r*3+2];
        float n = sqrtf(dx*dx + dy*dy + dz*dz);
        float rx = dx/n, ry = dy/n, rz = dz/n;
        ws[WS_RD + r*3+0] = rx; ws[WS_RD + r*3+1] = ry; ws[WS_RD + r*3+2] = rz;
        float ox = rays_o[r*3+0], oy = rays_o[r*3+1], oz = rays_o[r*3+2];
        float ivx = 1.0f/rx, ivy = 1.0f/ry, ivz = 1.0f/rz;
        float mnx = fminf((-RADIUS_F - ox)*ivx, (RADIUS_F - ox)*ivx);
        float mny = fminf((-RADIUS_F - oy)*ivy, (RADIUS_F - oy)*ivy);
        float mnz = fminf((-RADIUS_F - oz)*ivz, (RADIUS_F - oz)*ivz);
        float tn = fmaxf(fmaxf(fmaxf(mnx, mny), mnz), 0.0f);
        ws[WS_TN + r] = tn;
        const float C0=0.28209479177387814f, C1=0.4886025119029199f;
        const float C20=1.0925484305920792f, C22=0.31539156525252005f, C24=0.5462742152960396f;
        float x = rx, y = ry, z = rz;
        float sh[9];
        sh[0] = C0;
        sh[1] = -C1*y;
        sh[2] =  C1*z;
        sh[3] = -C1*x;
        sh[4] =  C20*x*y;
        sh[5] = -C20*y*z;
        sh[6] =  C22*(2.0f*z*z - x*x - y*y);
        sh[7] = -C20*x*z;
        sh[8] =  C24*(x*x - y*y);
        #pragma unroll
        for (int j = 0; j < 9; ++j) ws[WS_SHM + r*9 + j] = sh[j];
    }
    int e = gid - NB;
    if (e >= 0 && e < NUM_EMB) {
        float s = 0.0f;
        #pragma unroll 8
        for (int k = 0; k < EMB_DIM; ++k) { float v = emb[e*EMB_DIM + k]; s += v*v; }
        ws[WS_E2 + e] = s;
    }
}

// ---------- Kernel B: fused per-point pipeline, one wave per block ----------
// Round-14 passing structure. ONE change: the VQ scan reads emb via
// wave-uniform GLOBAL pointers (compiler emits s_load from K$/L2 on the
// SMEM pipe) instead of 8192 broadcast ds_read_b128 on the shared LDS unit.
// LDS tile staging + its syncs deleted. Everything else byte-identical.
__global__ __launch_bounds__(64) void point_kernel(
    const float* __restrict__ rays_o,
    const float* __restrict__ data,
    const float* __restrict__ emb,
    const float* __restrict__ W1, const float* __restrict__ b1,
    const float* __restrict__ W2, const float* __restrict__ b2,
    const float* __restrict__ W3, const float* __restrict__ b3,
    float* __restrict__ ws)
{
    __shared__ float smem[64*68];   // cls rows; later 512-bin hist overlay

    const int tid = threadIdx.x;   // 0..63
    const int ray = blockIdx.y;
    const int s   = blockIdx.x * 64 + tid;
    const bool live = (s < NINT);
    const int  ss = live ? s : (NINT - 1);

    // wave-uniform ray data
    const float rx = ws[WS_RD + ray*3+0];
    const float ry = ws[WS_RD + ray*3+1];
    const float rz = ws[WS_RD + ray*3+2];
    const float tn = ws[WS_TN + ray];
    const float ox = rays_o[ray*3+0], oy = rays_o[ray*3+1], oz = rays_o[ray*3+2];

    const float t  = tn + STEP_F * (float)ss;
    const float px = ox + t*rx, py = oy + t*ry, pz = oz + t*rz;
    const bool mask = live && (fabsf(px) < RADIUS_F) && (fabsf(py) < RADIUS_F) && (fabsf(pz) < RADIUS_F);

    // ---- dead-wave early exit ----
    unsigned long long alive = __ballot(mask);
    if (alive == 0ull) {
        if (live) {
            float4 z4; z4.x = 0.0f; z4.y = 0.0f; z4.z = 0.0f; z4.w = 0.0f;
            ((float4*)(ws + WS_RGBS))[ray*NINT + s] = z4;
        }
        return;
    }

    // trilinear coords
    float ix = fminf(fmaxf((px/RADIUS_F + 1.0f)*0.5f*63.0f, 0.0f), 63.0f);
    float iy = fminf(fmaxf((py/RADIUS_F + 1.0f)*0.5f*63.0f, 0.0f), 63.0f);
    float iz = fminf(fmaxf((pz/RADIUS_F + 1.0f)*0.5f*63.0f, 0.0f), 63.0f);
    int x0 = (int)floorf(ix); float wx = ix - (float)x0; int x1 = x0+1 > 63 ? 63 : x0+1;
    int y0 = (int)floorf(iy); float wy = iy - (float)y0; int y1 = y0+1 > 63 ? 63 : y0+1;
    int z0 = (int)floorf(iz); float wz = iz - (float)z0; int z1 = z0+1 > 63 ? 63 : z0+1;
    const int b000 = z0*4096 + y0*64 + x0;
    const int dxo = x1 - x0;
    const int dyo = (y1 - y0)*64;
    const int dzo = (z1 - z0)*4096;
    const float omwx = 1.0f-wx, omwy = 1.0f-wy, omwz = 1.0f-wz;

    // ---- interp: ROLLED loop, each channel retires to LDS ----
    float* myrow = smem + tid*68;
    #pragma unroll 4
    for (int c = 0; c < EMB_DIM; ++c) {
        const float* dc = data + c*262144 + b000;
        float v000 = dc[0],       v001 = dc[dxo];
        float v010 = dc[dyo],     v011 = dc[dyo+dxo];
        float v100 = dc[dzo],     v101 = dc[dzo+dxo];
        float v110 = dc[dzo+dyo], v111 = dc[dzo+dyo+dxo];
        float c00 = v000*omwx + v001*wx;
        float c01 = v010*omwx + v011*wx;
        float c10 = v100*omwx + v101*wx;
        float c11 = v110*omwx + v111*wx;
        myrow[c] = (c00*omwy + c01*wy)*omwz + (c10*omwy + c11*wy)*wz;
    }
    __syncthreads();

    // ---- rehydrate coarse[64] into registers (16 static b128 reads) ----
    float coarse[EMB_DIM];
    #pragma unroll
    for (int k4 = 0; k4 < 16; ++k4) {
        float4 v = *(const float4*)(myrow + k4*4);
        coarse[k4*4+0] = v.x; coarse[k4*4+1] = v.y;
        coarse[k4*4+2] = v.z; coarse[k4*4+3] = v.w;
    }
    __syncthreads();   // cls now dead; hist overlay safe later

    // ---- VQ argmin over 512 codes; emb via wave-uniform global (s_load/K$) ----
    float best = 3.4e38f; int bc = 0;
    const float* e2g = ws + WS_E2;
    for (int c = 0; c < NUM_EMB; c += 4) {
        const float4* er0 = (const float4*)(emb + (c+0)*EMB_DIM);
        const float4* er1 = (const float4*)(emb + (c+1)*EMB_DIM);
        const float4* er2 = (const float4*)(emb + (c+2)*EMB_DIM);
        const float4* er3 = (const float4*)(emb + (c+3)*EMB_DIM);
        float d0 = 0.0f, d1 = 0.0f, d2 = 0.0f, d3 = 0.0f;
        #pragma unroll
        for (int k4 = 0; k4 < 16; ++k4) {
            float4 e0 = er0[k4], e1 = er1[k4], e2v = er2[k4], e3 = er3[k4];
            float c0v = coarse[4*k4+0], c1v = coarse[4*k4+1];
            float c2v = coarse[4*k4+2], c3v = coarse[4*k4+3];
            d0 = fmaf(c0v, e0.x, d0); d0 = fmaf(c1v, e0.y, d0);
            d0 = fmaf(c2v, e0.z, d0); d0 = fmaf(c3v, e0.w, d0);
            d1 = fmaf(c0v, e1.x, d1); d1 = fmaf(c1v, e1.y, d1);
            d1 = fmaf(c2v, e1.z, d1); d1 = fmaf(c3v, e1.w, d1);
            d2 = fmaf(c0v, e2v.x, d2); d2 = fmaf(c1v, e2v.y, d2);
            d2 = fmaf(c2v, e2v.z, d2); d2 = fmaf(c3v, e2v.w, d2);
            d3 = fmaf(c0v, e3.x, d3); d3 = fmaf(c1v, e3.y, d3);
            d3 = fmaf(c2v, e3.z, d3); d3 = fmaf(c3v, e3.w, d3);
        }
        float4 ee = *(const float4*)(e2g + c);
        float s0 = ee.x - 2.0f*d0;
        float s1 = ee.y - 2.0f*d1;
        float s2 = ee.z - 2.0f*d2;
        float s3 = ee.w - 2.0f*d3;
        if (s0 < best) { best = s0; bc = c + 0; }
        if (s1 < best) { best = s1; bc = c + 1; }
        if (s2 < best) { best = s2; bc = c + 2; }
        if (s3 < best) { best = s3; bc = c + 3; }
    }

    // ---- privatized counts histogram (cls region dead) ----
    {
        float* hist = smem;   // 512 bins
        #pragma unroll
        for (int i = 0; i < 8; ++i) hist[tid + i*64] = 0.0f;
        __syncthreads();
        if (mask) atomicAdd(&hist[bc], 1.0f);
        __syncthreads();
        #pragma unroll
        for (int i = 0; i < 8; ++i) {
            float h = hist[tid + i*64];
            if (h != 0.0f) atomicAdd(&ws[WS_CNT + tid + i*64], h);
        }
    }

    // ---- MLP layer 1 fused with quant_st + e-loss (phase A: k=0..63) ----
    float h1[32];
    #pragma unroll
    for (int j = 0; j < 32; ++j) h1[j] = b1[j];

    float diff2 = 0.0f;
    {
        const float4* eq4 = (const float4*)(emb + bc*EMB_DIM);
        #pragma unroll
        for (int k4 = 0; k4 < 16; ++k4) {
            float4 q4 = eq4[k4];
            float q[4] = {q4.x, q4.y, q4.z, q4.w};
            #pragma unroll
            for (int u = 0; u < 4; ++u) {
                int k = k4*4 + u;
                float d  = q[u] - coarse[k];
                diff2 += d*d;
                float xv = coarse[k] + d;   // quant_st, matches fl(coarse + (q - coarse))
                #pragma unroll
                for (int j = 0; j < 32; ++j) h1[j] = fmaf(xv, W1[k*32 + j], h1[j]);
            }
        }
    }
    float el = mask ? diff2 : 0.0f;
    el = wave_reduce_sum(el);
    if (tid == 0 && el != 0.0f) atomicAdd(&ws[WS_ELOSS], el);

    // ---- phase B: positional encodings streamed into layer 1 ----
    {
        float fx = px*PCC_SC + 32.0f; fx = (fx - floorf(fx))*2.0f - 1.0f;
        float fy = py*PCC_SC + 32.0f; fy = (fy - floorf(fy))*2.0f - 1.0f;
        float fz = pz*PCC_SC + 32.0f; fz = (fz - floorf(fz))*2.0f - 1.0f;
        float fv[3] = {fx, fy, fz};
        float dv[3] = {rx, ry, rz};
        #pragma unroll
        for (int a = 0; a < 3; ++a) {
            #pragma unroll
            for (int f = 0; f < 4; ++f) {
                float angf = fv[a] * (float)(1 << f);
                float angd = dv[a] * (float)(1 << f);
                float sf = sinf(angf), cf = cosf(angf);
                float sd = sinf(angd), cd = cosf(angd);
                int rowS = 64 + a*8 + f;
                int rowC = rowS + 4;
                int rowSD = 88 + a*8 + f;
                int rowCD = rowSD + 4;
                #pragma unroll
                for (int j = 0; j < 32; ++j) {
                    h1[j] = fmaf(sf, W1[rowS*32 + j], h1[j]);
                    h1[j] = fmaf(cf, W1[rowC*32 + j], h1[j]);
                    h1[j] = fmaf(sd, W1[rowSD*32 + j], h1[j]);
                    h1[j] = fmaf(cd, W1[rowCD*32 + j], h1[j]);
                }
            }
        }
    }
    #pragma unroll
    for (int j = 0; j < 32; ++j) h1[j] = fmaxf(h1[j], 0.0f);

    // layer 2: 32 -> 32
    float h2[32];
    #pragma unroll
    for (int j = 0; j < 32; ++j) h2[j] = b2[j];
    #pragma unroll
    for (int k = 0; k < 32; ++k) {
        float hv = h1[k];
        #pragma unroll
        for (int j = 0; j < 32; ++j) h2[j] = fmaf(hv, W2[k*32 + j], h2[j]);
    }
    #pragma unroll
    for (int j = 0; j < 32; ++j) h2[j] = fmaxf(h2[j], 0.0f);

    // layer 3: 32 -> 28
    float shd[28];
    #pragma unroll
    for (int j = 0; j < 28; ++j) shd[j] = b3[j];
    #pragma unroll
    for (int k = 0; k < 32; ++k) {
        float hv = h2[k];
        #pragma unroll
        for (int j = 0; j < 28; ++j) shd[j] = fmaf(hv, W3[k*28 + j], shd[j]);
    }

    const float mf = mask ? 1.0f : 0.0f;
    float sigma = fmaxf(shd[27], 0.0f) * mf;

    float shm_[9];
    #pragma unroll
    for (int j = 0; j < 9; ++j) shm_[j] = ws[WS_SHM + ray*9 + j];

    float rgb[3];
    #pragma unroll
    for (int c = 0; c < 3; ++c) {
        float acc = 0.0f;
        #pragma unroll
        for (int j = 0; j < 9; ++j) acc = fmaf(shm_[j], shd[c*9 + j], acc);
        rgb[c] = fminf(fmaxf(acc*mf + 0.5f, 0.0f), 1.0f);
    }

    if (live) {
        float4 o4; o4.x = rgb[0]; o4.y = rgb[1]; o4.z = rgb[2]; o4.w = sigma;
        ((float4*)(ws + WS_RGBS))[ray*NINT + s] = o4;   // ray-major
    }
}

// ---------- Kernel C: per-ray compositing, one wave per ray ----------
__global__ void composite_kernel(const float* __restrict__ ws, float* __restrict__ out) {
    const int lane = threadIdx.x & 63;
    const int wid  = threadIdx.x >> 6;
    const int r = blockIdx.x * (blockDim.x >> 6) + wid;
    if (r >= NB) return;

    const float tn = ws[WS_TN + r];
    const float4* rs = ((const float4*)(ws + WS_RGBS)) + r*NINT;

    const int s0 = lane * 14;
    float T = 1.0f, c0 = 0.0f, c1 = 0.0f, c2 = 0.0f, dep = 0.0f, wsum = 0.0f;
    #pragma unroll 2
    for (int i = 0; i < 14; ++i) {
        int s = s0 + i;
        if (s < NINT) {
            float4 v = rs[s];
            float alpha = 1.0f - expf(-v.w * STEP_F);
            float w = alpha * T;
            c0 += w * v.x; c1 += w * v.y; c2 += w * v.z;
            dep  += w * (tn + STEP_F * (float)s);
            wsum += w;
            T *= (1.0f - alpha + 1e-10f);
        }
    }

    float inc = T;
    #pragma unroll
    for (int off = 1; off < 64; off <<= 1) {
        float o = __shfl_up(inc, off, 64);
        if (lane >= off) inc *= o;
    }
    float excl = __shfl_up(inc, 1, 64);
    if (lane == 0) excl = 1.0f;

    c0 *= excl; c1 *= excl; c2 *= excl; dep *= excl; wsum *= excl;
    c0 = wave_reduce_sum(c0);
    c1 = wave_reduce_sum(c1);
    c2 = wave_reduce_sum(c2);
    dep = wave_reduce_sum(dep);
    wsum = wave_reduce_sum(wsum);

    if (lane == 0) {
        float bg = 1.0f - wsum;
        out[r*3+0] = c0 + bg;
        out[r*3+1] = c1 + bg;
        out[r*3+2] = c2 + bg;
        out[768 + r] = dep;
    }
}

// ---------- Kernel D: loss + perplexity ----------
__global__ void finalize_kernel(const float* __restrict__ ws, float* __restrict__ out) {
    __shared__ float red[512];
    int t = threadIdx.x;
    float c = ws[WS_CNT + t];
    red[t] = c;
    __syncthreads();
    #pragma unroll
    for (int off = 256; off > 0; off >>= 1) {
        if (t < off) red[t] += red[t + off];
        __syncthreads();
    }
    float cnt = fmaxf(red[0], 1.0f);
    __syncthreads();
    float avg = c / cnt;
    red[t] = avg * logf(avg + 1e-10f);
    __syncthreads();
    #pragma unroll
    for (int off = 256; off > 0; off >>= 1) {
        if (t < off) red[t] += red[t + off];
        __syncthreads();
    }
    if (t == 0) {
        out[1024] = 0.25f * ws[WS_ELOSS] / (cnt * 64.0f);
        out[1025] = expf(-red[0]);
    }
}

extern "C" void kernel_launch(void* const* d_in, const int* in_sizes, int n_in,
                              void* d_out, int out_size, void* d_ws, size_t ws_size,
                              hipStream_t stream) {
    const float* rays_o = (const float*)d_in[0];
    const float* rays_d = (const float*)d_in[1];
    // d_in[2] = grid_id (int, unused)
    const float* data   = (const float*)d_in[3];
    const float* emb    = (const float*)d_in[4];
    const float* W1 = (const float*)d_in[5];
    const float* b1 = (const float*)d_in[6];
    const float* W2 = (const float*)d_in[7];
    const float* b2 = (const float*)d_in[8];
    const float* W3 = (const float*)d_in[9];
    const float* b3 = (const float*)d_in[10];
    float* ws  = (float*)d_ws;
    float* out = (float*)d_out;

    // zero the atomic accumulators (counts + eloss) every call
    hipMemsetAsync(ws + WS_CNT, 0, (NUM_EMB + 1) * sizeof(float), stream);

    setup_kernel<<<3, 256, 0, stream>>>(rays_o, rays_d, emb, ws);

    dim3 gB((NINT + 63) / 64, NB);   // 14 x 256 blocks, 64 threads each
    point_kernel<<<gB, 64, 0, stream>>>(rays_o, data, emb, W1, b1, W2, b2, W3, b3, ws);

    composite_kernel<<<64, 256, 0, stream>>>(ws, out);
    finalize_kernel<<<1, 512, 0, stream>>>(ws, out);
}